// Round 1
// baseline (155.027 us; speedup 1.0000x reference)
//
#include <hip/hip_runtime.h>
#include <math.h>

#define B_IMG 16
#define HW 409600
#define P_BLK 200            // blocks per image
#define TPB 256
#define F4_PER_BLK 512       // HW / P_BLK / 4
#define GRID (B_IMG * P_BLK) // 3200

// workspace layout (bytes)
#define OFF_GEO   0                          // 3200 doubles
#define OFF_DICE  25600                      // 3200*3 doubles
#define OFF_CNT   102400                     // 16*2 u32
#define OFF_STATE 102528                     // 16*8 u32
#define OFF_HA    103040                     // 16*2048 u32
#define OFF_HB    234112                     // 16*2048 u32
#define OFF_H2    365184                     // 16*2048 u32
#define OFF_H3    496256                     // 16*1024 u32
#define WS_BYTES  561792

union F4 { float4 v; float f[4]; };

__device__ __forceinline__ unsigned fkey(float x) {
    unsigned b = __float_as_uint(x);
    return b ^ ((b & 0x80000000u) ? 0xFFFFFFFFu : 0x80000000u);
}
__device__ __forceinline__ float funkey(unsigned k) {
    unsigned b = (k & 0x80000000u) ? (k ^ 0x80000000u) : ~k;
    return __uint_as_float(b);
}

__device__ __forceinline__ double wred(double v) {
#pragma unroll
    for (int off = 32; off > 0; off >>= 1) v += __shfl_down(v, off);
    return v;
}

// find bin b and 1-based rank r such that the n-th largest candidate falls in
// bin b with rank r among that bin's elements. blockDim.x == 64, h in LDS.
__device__ void radix_scan(const unsigned* h, int NB, unsigned n,
                           unsigned& bin_out, unsigned& r_out, bool& tgt) {
    const int lane = threadIdx.x;
    const int seg = NB >> 6;
    const int base = lane * seg;
    unsigned segsum = 0;
    for (int j = 0; j < seg; ++j) segsum += h[base + j];
    unsigned suf = segsum;
#pragma unroll
    for (int off = 1; off < 64; off <<= 1) {
        unsigned v = __shfl_down(suf, off);
        if (lane + off < 64) suf += v;
    }
    unsigned above = suf - segsum;  // counts in higher segments
    tgt = (suf >= n) && (above < n);
    bin_out = 0; r_out = 0;
    if (tgt) {
        unsigned cum = above;
        for (int j = base + seg - 1; j >= base; --j) {
            unsigned cb = cum;
            cum += h[j];
            if (cum >= n) { bin_out = (unsigned)j; r_out = n - cb; break; }
        }
    }
}

// ---------------- K1: counts + pass-1 hists (all & neg) + geo loss ----------
__global__ void __launch_bounds__(TPB)
k_pass1(const float* __restrict__ ytc, const float* __restrict__ ypc,
        const float* __restrict__ ytg, const float* __restrict__ ypg,
        const float* __restrict__ tmk,
        unsigned* __restrict__ counts, unsigned* __restrict__ histA,
        unsigned* __restrict__ histB, double* __restrict__ geo_part) {
    __shared__ unsigned hA[2048], hB[2048];
    __shared__ unsigned cpos, cneg;
    __shared__ double gred[4];
    for (int j = threadIdx.x; j < 2048; j += TPB) { hA[j] = 0; hB[j] = 0; }
    if (threadIdx.x == 0) { cpos = 0; cneg = 0; }
    __syncthreads();

    const int img = blockIdx.x / P_BLK, blk = blockIdx.x % P_BLK;
    const int cbase = img * (HW / 4) + blk * F4_PER_BLK;
    const int gbase = img * 5 * (HW / 4) + blk * F4_PER_BLK;

    const float4* sc = (const float4*)ypc;
    const float4* gt = (const float4*)ytc;
    const float4* tm = (const float4*)tmk;
    const float4* tg = (const float4*)ytg;
    const float4* pg = (const float4*)ypg;

    unsigned pos = 0, neg = 0;
    double geo = 0.0;

#pragma unroll
    for (int k = 0; k < 2; ++k) {
        const int t = threadIdx.x + k * TPB;
        F4 s, g, m;
        F4 d1g_, d2g_, d3g_, d4g_, thg_, d1p_, d2p_, d3p_, d4p_, thp_;
        s.v = sc[cbase + t]; g.v = gt[cbase + t]; m.v = tm[cbase + t];
        d1g_.v = tg[gbase + 0 * (HW / 4) + t];
        d2g_.v = tg[gbase + 1 * (HW / 4) + t];
        d3g_.v = tg[gbase + 2 * (HW / 4) + t];
        d4g_.v = tg[gbase + 3 * (HW / 4) + t];
        thg_.v = tg[gbase + 4 * (HW / 4) + t];
        d1p_.v = pg[gbase + 0 * (HW / 4) + t];
        d2p_.v = pg[gbase + 1 * (HW / 4) + t];
        d3p_.v = pg[gbase + 2 * (HW / 4) + t];
        d4p_.v = pg[gbase + 3 * (HW / 4) + t];
        thp_.v = pg[gbase + 4 * (HW / 4) + t];
#pragma unroll
        for (int j = 0; j < 4; ++j) {
            const float sv = s.f[j], gv = g.f[j], mv = m.f[j];
            pos += (gv > 0.5f && mv > 0.5f) ? 1u : 0u;
            const bool isneg = (gv < 0.5f);
            neg += isneg ? 1u : 0u;
            const unsigned key = fkey(sv);
            atomicAdd(&hA[key >> 21], 1u);
            if (isneg) atomicAdd(&hB[key >> 21], 1u);

            const float ag = (d1g_.f[j] + d3g_.f[j]) * (d2g_.f[j] + d4g_.f[j]);
            const float ap = (d1p_.f[j] + d3p_.f[j]) * (d2p_.f[j] + d4p_.f[j]);
            const float wu = fminf(d2g_.f[j], d2p_.f[j]) + fminf(d4g_.f[j], d4p_.f[j]);
            const float hu = fminf(d1g_.f[j], d1p_.f[j]) + fminf(d3g_.f[j], d3p_.f[j]);
            const float ai = wu * hu;
            const float au = ag + ap - ai;
            const float la = -logf((ai + 1.0f) / (au + 1.0f));
            const float lt = 1.0f - cosf(thp_.f[j] - thg_.f[j]);
            geo += (double)((la + 20.0f * lt) * gv * mv);
        }
    }

    atomicAdd(&cpos, pos);
    atomicAdd(&cneg, neg);
    const double gw = wred(geo);
    const int lane = threadIdx.x & 63, wid = threadIdx.x >> 6;
    if (lane == 0) gred[wid] = gw;
    __syncthreads();
    if (threadIdx.x == 0) {
        geo_part[blockIdx.x] = gred[0] + gred[1] + gred[2] + gred[3];
        atomicAdd(&counts[img * 2 + 0], cpos);
        atomicAdd(&counts[img * 2 + 1], cneg);
    }
    for (int j = threadIdx.x; j < 2048; j += TPB) {
        const unsigned a = hA[j]; if (a) atomicAdd(&histA[img * 2048 + j], a);
        const unsigned b = hB[j]; if (b) atomicAdd(&histB[img * 2048 + j], b);
    }
}

// ---------------- scan 1: decide branch, pick pass-1 bucket -----------------
__global__ void k_scan1(const unsigned* __restrict__ counts,
                        const unsigned* __restrict__ histA,
                        const unsigned* __restrict__ histB,
                        unsigned* __restrict__ state) {
    const int img = blockIdx.x, lane = threadIdx.x;
    const unsigned pos = counts[img * 2 + 0], neg = counts[img * 2 + 1];
    unsigned branch, n = 1;
    if (pos == 0) {
        branch = 0;                      // mask1: top neg/2 of ALL scores
        n = neg / 2; if (n < 1) n = 1;
    } else {
        const unsigned n3 = min(pos * 3u, neg);
        if (n3 == 0) branch = 1;         // mask = training_mask
        else { branch = 2; n = n3; }     // mask3: top n3 of negative scores
    }
    if (branch == 1) { if (lane == 0) state[img * 8 + 0] = 1u; return; }
    __shared__ unsigned h[2048];
    const unsigned* g = (branch == 0 ? histA : histB) + img * 2048;
    for (int j = lane; j < 2048; j += 64) h[j] = g[j];
    __syncthreads();
    unsigned bin, r; bool tgt;
    radix_scan(h, 2048, n, bin, r, tgt);
    if (tgt) {
        state[img * 8 + 0] = branch;
        state[img * 8 + 1] = bin;
        state[img * 8 + 2] = r;
    }
}

// ---------------- pass 2 histogram (middle 11 bits) -------------------------
__global__ void __launch_bounds__(TPB)
k_hist2k(const float* __restrict__ ypc, const float* __restrict__ ytc,
         const unsigned* __restrict__ state, unsigned* __restrict__ hist2) {
    const int img = blockIdx.x / P_BLK, blk = blockIdx.x % P_BLK;
    const unsigned branch = state[img * 8 + 0];
    if (branch == 1) return;
    const unsigned pfx = state[img * 8 + 1];
    __shared__ unsigned h[2048];
    for (int j = threadIdx.x; j < 2048; j += TPB) h[j] = 0;
    __syncthreads();
    const int cbase = img * (HW / 4) + blk * F4_PER_BLK;
    const float4* sc = (const float4*)ypc;
    const float4* gt = (const float4*)ytc;
#pragma unroll
    for (int k = 0; k < 2; ++k) {
        const int t = threadIdx.x + k * TPB;
        F4 s, g; s.v = sc[cbase + t]; g.v = gt[cbase + t];
#pragma unroll
        for (int j = 0; j < 4; ++j) {
            const bool cand = (branch == 0) || (g.f[j] < 0.5f);
            const unsigned key = fkey(s.f[j]);
            if (cand && (key >> 21) == pfx) atomicAdd(&h[(key >> 10) & 2047u], 1u);
        }
    }
    __syncthreads();
    for (int j = threadIdx.x; j < 2048; j += TPB) {
        const unsigned v = h[j]; if (v) atomicAdd(&hist2[img * 2048 + j], v);
    }
}

__global__ void k_scan2(unsigned* __restrict__ state, const unsigned* __restrict__ hist2) {
    const int img = blockIdx.x, lane = threadIdx.x;
    const unsigned branch = state[img * 8 + 0];
    if (branch == 1) return;
    const unsigned n = state[img * 8 + 2];
    __shared__ unsigned h[2048];
    const unsigned* g = hist2 + img * 2048;
    for (int j = lane; j < 2048; j += 64) h[j] = g[j];
    __syncthreads();
    unsigned bin, r; bool tgt;
    radix_scan(h, 2048, n, bin, r, tgt);
    if (tgt) {
        state[img * 8 + 1] = (state[img * 8 + 1] << 11) | bin;
        state[img * 8 + 2] = r;
    }
}

// ---------------- pass 3 histogram (low 10 bits) ----------------------------
__global__ void __launch_bounds__(TPB)
k_hist3k(const float* __restrict__ ypc, const float* __restrict__ ytc,
         const unsigned* __restrict__ state, unsigned* __restrict__ hist3) {
    const int img = blockIdx.x / P_BLK, blk = blockIdx.x % P_BLK;
    const unsigned branch = state[img * 8 + 0];
    if (branch == 1) return;
    const unsigned pfx = state[img * 8 + 1];  // 22-bit prefix
    __shared__ unsigned h[1024];
    for (int j = threadIdx.x; j < 1024; j += TPB) h[j] = 0;
    __syncthreads();
    const int cbase = img * (HW / 4) + blk * F4_PER_BLK;
    const float4* sc = (const float4*)ypc;
    const float4* gt = (const float4*)ytc;
#pragma unroll
    for (int k = 0; k < 2; ++k) {
        const int t = threadIdx.x + k * TPB;
        F4 s, g; s.v = sc[cbase + t]; g.v = gt[cbase + t];
#pragma unroll
        for (int j = 0; j < 4; ++j) {
            const bool cand = (branch == 0) || (g.f[j] < 0.5f);
            const unsigned key = fkey(s.f[j]);
            if (cand && (key >> 10) == pfx) atomicAdd(&h[key & 1023u], 1u);
        }
    }
    __syncthreads();
    for (int j = threadIdx.x; j < 1024; j += TPB) {
        const unsigned v = h[j]; if (v) atomicAdd(&hist3[img * 1024 + j], v);
    }
}

__global__ void k_scan3(unsigned* __restrict__ state, const unsigned* __restrict__ hist3) {
    const int img = blockIdx.x, lane = threadIdx.x;
    const unsigned branch = state[img * 8 + 0];
    if (branch == 1) return;
    const unsigned n = state[img * 8 + 2];
    __shared__ unsigned h[1024];
    const unsigned* g = hist3 + img * 1024;
    for (int j = lane; j < 1024; j += 64) h[j] = g[j];
    __syncthreads();
    unsigned bin, r; bool tgt;
    radix_scan(h, 1024, n, bin, r, tgt);
    if (tgt) {
        const unsigned key = (state[img * 8 + 1] << 10) | bin;
        state[img * 8 + 4] = __float_as_uint(funkey(key));
    }
}

// ---------------- final: OHEM mask on the fly + dice partial sums -----------
__global__ void __launch_bounds__(TPB)
k_final(const float* __restrict__ ytc, const float* __restrict__ ypc,
        const float* __restrict__ tmk, const unsigned* __restrict__ state,
        double* __restrict__ dice_part) {
    const int img = blockIdx.x / P_BLK, blk = blockIdx.x % P_BLK;
    const unsigned branch = state[img * 8 + 0];
    const float thr = __uint_as_float(state[img * 8 + 4]);
    const int cbase = img * (HW / 4) + blk * F4_PER_BLK;
    const float4* sc = (const float4*)ypc;
    const float4* gt = (const float4*)ytc;
    const float4* tm = (const float4*)tmk;
    double di = 0.0, dg = 0.0, dp = 0.0;
#pragma unroll
    for (int k = 0; k < 2; ++k) {
        const int t = threadIdx.x + k * TPB;
        F4 s, g, m; s.v = sc[cbase + t]; g.v = gt[cbase + t]; m.v = tm[cbase + t];
#pragma unroll
        for (int j = 0; j < 4; ++j) {
            const float sv = s.f[j], gv = g.f[j], mv = m.f[j];
            float mm;
            if (branch == 0)      mm = (sv >= thr) ? 1.0f : 0.0f;
            else if (branch == 1) mm = mv;
            else                  mm = (((sv >= thr) || (gv > 0.5f)) && (mv > 0.5f)) ? 1.0f : 0.0f;
            di += (double)(gv * sv * mm);
            dg += (double)(gv * mm);
            dp += (double)(sv * mm);
        }
    }
    const double a = wred(di), b = wred(dg), c = wred(dp);
    __shared__ double r[4][3];
    const int lane = threadIdx.x & 63, wid = threadIdx.x >> 6;
    if (lane == 0) { r[wid][0] = a; r[wid][1] = b; r[wid][2] = c; }
    __syncthreads();
    if (threadIdx.x == 0) {
        dice_part[blockIdx.x * 3 + 0] = r[0][0] + r[1][0] + r[2][0] + r[3][0];
        dice_part[blockIdx.x * 3 + 1] = r[0][1] + r[1][1] + r[2][1] + r[3][1];
        dice_part[blockIdx.x * 3 + 2] = r[0][2] + r[1][2] + r[2][2] + r[3][2];
    }
}

// ---------------- combine ---------------------------------------------------
__global__ void __launch_bounds__(256)
k_out(const double* __restrict__ geo_part, const double* __restrict__ dice_part,
      float* __restrict__ out) {
    double geo = 0.0, di = 0.0, dg = 0.0, dp = 0.0;
    for (int i = threadIdx.x; i < GRID; i += 256) {
        geo += geo_part[i];
        di += dice_part[i * 3 + 0];
        dg += dice_part[i * 3 + 1];
        dp += dice_part[i * 3 + 2];
    }
    geo = wred(geo); di = wred(di); dg = wred(dg); dp = wred(dp);
    __shared__ double r[4][4];
    const int lane = threadIdx.x & 63, wid = threadIdx.x >> 6;
    if (lane == 0) { r[wid][0] = geo; r[wid][1] = di; r[wid][2] = dg; r[wid][3] = dp; }
    __syncthreads();
    if (threadIdx.x == 0) {
        geo = r[0][0] + r[1][0] + r[2][0] + r[3][0];
        di  = r[0][1] + r[1][1] + r[2][1] + r[3][1];
        dg  = r[0][2] + r[1][2] + r[2][2] + r[3][2];
        dp  = r[0][3] + r[1][3] + r[2][3] + r[3][3];
        const double mean = geo / (double)((double)B_IMG * (double)HW);
        const double uni = dg + dp + 1e-05;
        const double loss = mean + 0.01 * (1.0 - 2.0 * di / uni);
        out[0] = (float)loss;
    }
}

extern "C" void kernel_launch(void* const* d_in, const int* in_sizes, int n_in,
                              void* d_out, int out_size, void* d_ws, size_t ws_size,
                              hipStream_t stream) {
    const float* ytc = (const float*)d_in[0];  // y_true_cls  (gt)
    const float* ypc = (const float*)d_in[1];  // y_pred_cls  (score)
    const float* ytg = (const float*)d_in[2];  // y_true_geo
    const float* ypg = (const float*)d_in[3];  // y_pred_geo
    const float* tmk = (const float*)d_in[4];  // training_mask

    char* ws = (char*)d_ws;
    double*   geo_part  = (double*)(ws + OFF_GEO);
    double*   dice_part = (double*)(ws + OFF_DICE);
    unsigned* counts    = (unsigned*)(ws + OFF_CNT);
    unsigned* state     = (unsigned*)(ws + OFF_STATE);
    unsigned* histA     = (unsigned*)(ws + OFF_HA);
    unsigned* histB     = (unsigned*)(ws + OFF_HB);
    unsigned* hist2     = (unsigned*)(ws + OFF_H2);
    unsigned* hist3     = (unsigned*)(ws + OFF_H3);

    hipMemsetAsync(d_ws, 0, WS_BYTES, stream);

    k_pass1<<<GRID, TPB, 0, stream>>>(ytc, ypc, ytg, ypg, tmk,
                                      counts, histA, histB, geo_part);
    k_scan1<<<B_IMG, 64, 0, stream>>>(counts, histA, histB, state);
    k_hist2k<<<GRID, TPB, 0, stream>>>(ypc, ytc, state, hist2);
    k_scan2<<<B_IMG, 64, 0, stream>>>(state, hist2);
    k_hist3k<<<GRID, TPB, 0, stream>>>(ypc, ytc, state, hist3);
    k_scan3<<<B_IMG, 64, 0, stream>>>(state, hist3);
    k_final<<<GRID, TPB, 0, stream>>>(ytc, ypc, tmk, state, dice_part);
    k_out<<<1, 256, 0, stream>>>(geo_part, dice_part, (float*)d_out);
}

// Round 2
// 144.496 us; speedup vs baseline: 1.0729x; 1.0729x over previous
//
#include <hip/hip_runtime.h>
#include <math.h>

#define B_IMG 16
#define HW 409600
#define HW4 102400           // HW/4
#define P_BLK 128            // blocks per image
#define TPB 256
#define F4_PER_BLK 800       // HW4 / P_BLK
#define NBLK (B_IMG * P_BLK) // 2048

// workspace layout (bytes)
#define OFF_GEO   0                          // 2048 doubles
#define OFF_DICE  16384                      // 2048*3 doubles
#define OFF_CNT   65536                      // 16*2 u32
#define OFF_STATE 65664                      // 16*8 u32
#define OFF_H1    66176                      // 16*2048 u32
#define OFF_H2    197248                     // 16*2048 u32
#define OFF_H3    328320                     // 16*1024 u32
#define WS_BYTES  393856

union F4 { float4 v; float f[4]; };

__device__ __forceinline__ unsigned fkey(float x) {
    unsigned b = __float_as_uint(x);
    return b ^ ((b & 0x80000000u) ? 0xFFFFFFFFu : 0x80000000u);
}
__device__ __forceinline__ float funkey(unsigned k) {
    unsigned b = (k & 0x80000000u) ? (k ^ 0x80000000u) : ~k;
    return __uint_as_float(b);
}

__device__ __forceinline__ double wredd(double v) {
#pragma unroll
    for (int off = 32; off > 0; off >>= 1) v += __shfl_down(v, off);
    return v;
}
__device__ __forceinline__ unsigned wredu(unsigned v) {
#pragma unroll
    for (int off = 32; off > 0; off >>= 1) v += __shfl_down(v, off);
    return v;
}

// find bin b and 1-based rank r such that the n-th largest candidate falls in
// bin b with rank r among that bin's elements. blockDim.x == 64, h in LDS.
__device__ void radix_scan(const unsigned* h, int NB, unsigned n,
                           unsigned& bin_out, unsigned& r_out, bool& tgt) {
    const int lane = threadIdx.x;
    const int seg = NB >> 6;
    const int base = lane * seg;
    unsigned segsum = 0;
    for (int j = 0; j < seg; ++j) segsum += h[base + j];
    unsigned suf = segsum;
#pragma unroll
    for (int off = 1; off < 64; off <<= 1) {
        unsigned v = __shfl_down(suf, off);
        if (lane + off < 64) suf += v;
    }
    unsigned above = suf - segsum;  // counts in higher segments
    tgt = (suf >= n) && (above < n);
    bin_out = 0; r_out = 0;
    if (tgt) {
        unsigned cum = above;
        for (int j = base + seg - 1; j >= base; --j) {
            unsigned cb = cum;
            cum += h[j];
            if (cum >= n) { bin_out = (unsigned)j; r_out = n - cb; break; }
        }
    }
}

// ---------- K1: pure streaming — pos/neg counts + geo loss (no LDS hist) ----
__global__ void __launch_bounds__(TPB)
k_geo(const float* __restrict__ ytc, const float* __restrict__ ytg,
      const float* __restrict__ ypg, const float* __restrict__ tmk,
      unsigned* __restrict__ counts, double* __restrict__ geo_part) {
    const int img = blockIdx.x >> 7, blk = blockIdx.x & 127;
    const int cbase = img * HW4 + blk * F4_PER_BLK;
    const int gbase = img * 5 * HW4 + blk * F4_PER_BLK;

    const float4* gt = (const float4*)ytc;
    const float4* tm = (const float4*)tmk;
    const float4* tg = (const float4*)ytg;
    const float4* pg = (const float4*)ypg;

    unsigned pos = 0, neg = 0;
    float geo_f = 0.0f;

#pragma unroll
    for (int k = 0; k < 4; ++k) {
        const int t = threadIdx.x + k * TPB;
        if (t < F4_PER_BLK) {
            F4 g, m, d1g_, d2g_, d3g_, d4g_, thg_, d1p_, d2p_, d3p_, d4p_, thp_;
            g.v = gt[cbase + t]; m.v = tm[cbase + t];
            d1g_.v = tg[gbase + 0 * HW4 + t];
            d2g_.v = tg[gbase + 1 * HW4 + t];
            d3g_.v = tg[gbase + 2 * HW4 + t];
            d4g_.v = tg[gbase + 3 * HW4 + t];
            thg_.v = tg[gbase + 4 * HW4 + t];
            d1p_.v = pg[gbase + 0 * HW4 + t];
            d2p_.v = pg[gbase + 1 * HW4 + t];
            d3p_.v = pg[gbase + 2 * HW4 + t];
            d4p_.v = pg[gbase + 3 * HW4 + t];
            thp_.v = pg[gbase + 4 * HW4 + t];
#pragma unroll
            for (int j = 0; j < 4; ++j) {
                const float gv = g.f[j], mv = m.f[j];
                pos += (gv > 0.5f && mv > 0.5f) ? 1u : 0u;
                neg += (gv < 0.5f) ? 1u : 0u;
                const float ag = (d1g_.f[j] + d3g_.f[j]) * (d2g_.f[j] + d4g_.f[j]);
                const float ap = (d1p_.f[j] + d3p_.f[j]) * (d2p_.f[j] + d4p_.f[j]);
                const float wu = fminf(d2g_.f[j], d2p_.f[j]) + fminf(d4g_.f[j], d4p_.f[j]);
                const float hu = fminf(d1g_.f[j], d1p_.f[j]) + fminf(d3g_.f[j], d3p_.f[j]);
                const float ai = wu * hu;
                const float au = ag + ap - ai;
                const float la = -__logf((ai + 1.0f) / (au + 1.0f));
                const float lt = 1.0f - __cosf(thp_.f[j] - thg_.f[j]);
                geo_f += (la + 20.0f * lt) * gv * mv;
            }
        }
    }

    const double gw = wredd((double)geo_f);
    const unsigned pw = wredu(pos), nw = wredu(neg);
    __shared__ double gred[4];
    __shared__ unsigned pr[4], nr[4];
    const int lane = threadIdx.x & 63, wid = threadIdx.x >> 6;
    if (lane == 0) { gred[wid] = gw; pr[wid] = pw; nr[wid] = nw; }
    __syncthreads();
    if (threadIdx.x == 0) {
        geo_part[blockIdx.x] = gred[0] + gred[1] + gred[2] + gred[3];
        atomicAdd(&counts[img * 2 + 0], pr[0] + pr[1] + pr[2] + pr[3]);
        atomicAdd(&counts[img * 2 + 1], nr[0] + nr[1] + nr[2] + nr[3]);
    }
}

// ---------- decide branch + initial n per image -----------------------------
__global__ void k_branch(const unsigned* __restrict__ counts,
                         unsigned* __restrict__ state) {
    const int img = threadIdx.x;
    if (img >= B_IMG) return;
    const unsigned pos = counts[img * 2 + 0], neg = counts[img * 2 + 1];
    unsigned branch, n = 1;
    if (pos == 0) {
        branch = 0;                      // mask1: top neg/2 of ALL scores
        n = neg / 2; if (n < 1) n = 1;
    } else {
        const unsigned n3 = min(pos * 3u, neg);
        if (n3 == 0) branch = 1;         // mask = training_mask
        else { branch = 2; n = n3; }     // mask3: top n3 of negative scores
    }
    state[img * 8 + 0] = branch;
    state[img * 8 + 2] = n;
}

// ---------- pass-1 histogram (top 11 bits), 4 lane-replicated copies --------
__global__ void __launch_bounds__(TPB)
k_hist1(const float* __restrict__ ypc, const float* __restrict__ ytc,
        const unsigned* __restrict__ state, unsigned* __restrict__ hist1) {
    const int img = blockIdx.x >> 7, blk = blockIdx.x & 127;
    const unsigned branch = state[img * 8 + 0];
    if (branch == 1) return;
    __shared__ unsigned h[4 * 2049];
    for (int j = threadIdx.x; j < 4 * 2049; j += TPB) h[j] = 0;
    __syncthreads();
    const int cbase = img * HW4 + blk * F4_PER_BLK;
    const int c = (threadIdx.x & 3) * 2049;
    const float4* sc = (const float4*)ypc;
    const float4* gt = (const float4*)ytc;
#pragma unroll
    for (int k = 0; k < 4; ++k) {
        const int t = threadIdx.x + k * TPB;
        if (t < F4_PER_BLK) {
            F4 s, g; s.v = sc[cbase + t]; g.v = gt[cbase + t];
#pragma unroll
            for (int j = 0; j < 4; ++j) {
                const bool cand = (branch == 0) || (g.f[j] < 0.5f);
                if (cand) atomicAdd(&h[c + (fkey(s.f[j]) >> 21)], 1u);
            }
        }
    }
    __syncthreads();
    for (int j = threadIdx.x; j < 2048; j += TPB) {
        const unsigned v = h[j] + h[j + 2049] + h[j + 2 * 2049] + h[j + 3 * 2049];
        if (v) atomicAdd(&hist1[img * 2048 + j], v);
    }
}

__global__ void k_scan1(unsigned* __restrict__ state, const unsigned* __restrict__ hist1) {
    const int img = blockIdx.x, lane = threadIdx.x;
    const unsigned branch = state[img * 8 + 0];
    if (branch == 1) return;
    const unsigned n = state[img * 8 + 2];
    __shared__ unsigned h[2048];
    const unsigned* g = hist1 + img * 2048;
    for (int j = lane; j < 2048; j += 64) h[j] = g[j];
    __syncthreads();
    unsigned bin, r; bool tgt;
    radix_scan(h, 2048, n, bin, r, tgt);
    if (tgt) { state[img * 8 + 1] = bin; state[img * 8 + 2] = r; }
}

// ---------- pass-2 histogram (middle 11 bits) -------------------------------
__global__ void __launch_bounds__(TPB)
k_hist2(const float* __restrict__ ypc, const float* __restrict__ ytc,
        const unsigned* __restrict__ state, unsigned* __restrict__ hist2) {
    const int img = blockIdx.x >> 7, blk = blockIdx.x & 127;
    const unsigned branch = state[img * 8 + 0];
    if (branch == 1) return;
    const unsigned pfx = state[img * 8 + 1];
    __shared__ unsigned h[2048];
    for (int j = threadIdx.x; j < 2048; j += TPB) h[j] = 0;
    __syncthreads();
    const int cbase = img * HW4 + blk * F4_PER_BLK;
    const float4* sc = (const float4*)ypc;
    const float4* gt = (const float4*)ytc;
#pragma unroll
    for (int k = 0; k < 4; ++k) {
        const int t = threadIdx.x + k * TPB;
        if (t < F4_PER_BLK) {
            F4 s, g; s.v = sc[cbase + t]; g.v = gt[cbase + t];
#pragma unroll
            for (int j = 0; j < 4; ++j) {
                const bool cand = (branch == 0) || (g.f[j] < 0.5f);
                const unsigned key = fkey(s.f[j]);
                if (cand && (key >> 21) == pfx) atomicAdd(&h[(key >> 10) & 2047u], 1u);
            }
        }
    }
    __syncthreads();
    for (int j = threadIdx.x; j < 2048; j += TPB) {
        const unsigned v = h[j]; if (v) atomicAdd(&hist2[img * 2048 + j], v);
    }
}

__global__ void k_scan2(unsigned* __restrict__ state, const unsigned* __restrict__ hist2) {
    const int img = blockIdx.x, lane = threadIdx.x;
    const unsigned branch = state[img * 8 + 0];
    if (branch == 1) return;
    const unsigned n = state[img * 8 + 2];
    __shared__ unsigned h[2048];
    const unsigned* g = hist2 + img * 2048;
    for (int j = lane; j < 2048; j += 64) h[j] = g[j];
    __syncthreads();
    unsigned bin, r; bool tgt;
    radix_scan(h, 2048, n, bin, r, tgt);
    if (tgt) {
        state[img * 8 + 1] = (state[img * 8 + 1] << 11) | bin;
        state[img * 8 + 2] = r;
    }
}

// ---------- pass-3 histogram (low 10 bits) ----------------------------------
__global__ void __launch_bounds__(TPB)
k_hist3(const float* __restrict__ ypc, const float* __restrict__ ytc,
        const unsigned* __restrict__ state, unsigned* __restrict__ hist3) {
    const int img = blockIdx.x >> 7, blk = blockIdx.x & 127;
    const unsigned branch = state[img * 8 + 0];
    if (branch == 1) return;
    const unsigned pfx = state[img * 8 + 1];  // 22-bit prefix
    __shared__ unsigned h[1024];
    for (int j = threadIdx.x; j < 1024; j += TPB) h[j] = 0;
    __syncthreads();
    const int cbase = img * HW4 + blk * F4_PER_BLK;
    const float4* sc = (const float4*)ypc;
    const float4* gt = (const float4*)ytc;
#pragma unroll
    for (int k = 0; k < 4; ++k) {
        const int t = threadIdx.x + k * TPB;
        if (t < F4_PER_BLK) {
            F4 s, g; s.v = sc[cbase + t]; g.v = gt[cbase + t];
#pragma unroll
            for (int j = 0; j < 4; ++j) {
                const bool cand = (branch == 0) || (g.f[j] < 0.5f);
                const unsigned key = fkey(s.f[j]);
                if (cand && (key >> 10) == pfx) atomicAdd(&h[key & 1023u], 1u);
            }
        }
    }
    __syncthreads();
    for (int j = threadIdx.x; j < 1024; j += TPB) {
        const unsigned v = h[j]; if (v) atomicAdd(&hist3[img * 1024 + j], v);
    }
}

__global__ void k_scan3(unsigned* __restrict__ state, const unsigned* __restrict__ hist3) {
    const int img = blockIdx.x, lane = threadIdx.x;
    const unsigned branch = state[img * 8 + 0];
    if (branch == 1) return;
    const unsigned n = state[img * 8 + 2];
    __shared__ unsigned h[1024];
    const unsigned* g = hist3 + img * 1024;
    for (int j = lane; j < 1024; j += 64) h[j] = g[j];
    __syncthreads();
    unsigned bin, r; bool tgt;
    radix_scan(h, 1024, n, bin, r, tgt);
    if (tgt) {
        const unsigned key = (state[img * 8 + 1] << 10) | bin;
        state[img * 8 + 4] = __float_as_uint(funkey(key));
    }
}

// ---------- final: OHEM mask on the fly + dice partial sums -----------------
__global__ void __launch_bounds__(TPB)
k_final(const float* __restrict__ ytc, const float* __restrict__ ypc,
        const float* __restrict__ tmk, const unsigned* __restrict__ state,
        double* __restrict__ dice_part) {
    const int img = blockIdx.x >> 7, blk = blockIdx.x & 127;
    const unsigned branch = state[img * 8 + 0];
    const float thr = __uint_as_float(state[img * 8 + 4]);
    const int cbase = img * HW4 + blk * F4_PER_BLK;
    const float4* sc = (const float4*)ypc;
    const float4* gt = (const float4*)ytc;
    const float4* tm = (const float4*)tmk;
    float di = 0.0f, dg = 0.0f, dp = 0.0f;
#pragma unroll
    for (int k = 0; k < 4; ++k) {
        const int t = threadIdx.x + k * TPB;
        if (t < F4_PER_BLK) {
            F4 s, g, m; s.v = sc[cbase + t]; g.v = gt[cbase + t]; m.v = tm[cbase + t];
#pragma unroll
            for (int j = 0; j < 4; ++j) {
                const float sv = s.f[j], gv = g.f[j], mv = m.f[j];
                float mm;
                if (branch == 0)      mm = (sv >= thr) ? 1.0f : 0.0f;
                else if (branch == 1) mm = mv;
                else                  mm = (((sv >= thr) || (gv > 0.5f)) && (mv > 0.5f)) ? 1.0f : 0.0f;
                di += gv * sv * mm;
                dg += gv * mm;
                dp += sv * mm;
            }
        }
    }
    const double a = wredd((double)di), b = wredd((double)dg), c = wredd((double)dp);
    __shared__ double r[4][3];
    const int lane = threadIdx.x & 63, wid = threadIdx.x >> 6;
    if (lane == 0) { r[wid][0] = a; r[wid][1] = b; r[wid][2] = c; }
    __syncthreads();
    if (threadIdx.x == 0) {
        dice_part[blockIdx.x * 3 + 0] = r[0][0] + r[1][0] + r[2][0] + r[3][0];
        dice_part[blockIdx.x * 3 + 1] = r[0][1] + r[1][1] + r[2][1] + r[3][1];
        dice_part[blockIdx.x * 3 + 2] = r[0][2] + r[1][2] + r[2][2] + r[3][2];
    }
}

// ---------- combine ---------------------------------------------------------
__global__ void __launch_bounds__(256)
k_out(const double* __restrict__ geo_part, const double* __restrict__ dice_part,
      float* __restrict__ out) {
    double geo = 0.0, di = 0.0, dg = 0.0, dp = 0.0;
    for (int i = threadIdx.x; i < NBLK; i += 256) {
        geo += geo_part[i];
        di += dice_part[i * 3 + 0];
        dg += dice_part[i * 3 + 1];
        dp += dice_part[i * 3 + 2];
    }
    geo = wredd(geo); di = wredd(di); dg = wredd(dg); dp = wredd(dp);
    __shared__ double r[4][4];
    const int lane = threadIdx.x & 63, wid = threadIdx.x >> 6;
    if (lane == 0) { r[wid][0] = geo; r[wid][1] = di; r[wid][2] = dg; r[wid][3] = dp; }
    __syncthreads();
    if (threadIdx.x == 0) {
        geo = r[0][0] + r[1][0] + r[2][0] + r[3][0];
        di  = r[0][1] + r[1][1] + r[2][1] + r[3][1];
        dg  = r[0][2] + r[1][2] + r[2][2] + r[3][2];
        dp  = r[0][3] + r[1][3] + r[2][3] + r[3][3];
        const double mean = geo / (double)((double)B_IMG * (double)HW);
        const double uni = dg + dp + 1e-05;
        const double loss = mean + 0.01 * (1.0 - 2.0 * di / uni);
        out[0] = (float)loss;
    }
}

extern "C" void kernel_launch(void* const* d_in, const int* in_sizes, int n_in,
                              void* d_out, int out_size, void* d_ws, size_t ws_size,
                              hipStream_t stream) {
    const float* ytc = (const float*)d_in[0];  // y_true_cls  (gt)
    const float* ypc = (const float*)d_in[1];  // y_pred_cls  (score)
    const float* ytg = (const float*)d_in[2];  // y_true_geo
    const float* ypg = (const float*)d_in[3];  // y_pred_geo
    const float* tmk = (const float*)d_in[4];  // training_mask

    char* ws = (char*)d_ws;
    double*   geo_part  = (double*)(ws + OFF_GEO);
    double*   dice_part = (double*)(ws + OFF_DICE);
    unsigned* counts    = (unsigned*)(ws + OFF_CNT);
    unsigned* state     = (unsigned*)(ws + OFF_STATE);
    unsigned* hist1     = (unsigned*)(ws + OFF_H1);
    unsigned* hist2     = (unsigned*)(ws + OFF_H2);
    unsigned* hist3     = (unsigned*)(ws + OFF_H3);

    hipMemsetAsync(d_ws, 0, WS_BYTES, stream);

    k_geo<<<NBLK, TPB, 0, stream>>>(ytc, ytg, ypg, tmk, counts, geo_part);
    k_branch<<<1, 64, 0, stream>>>(counts, state);
    k_hist1<<<NBLK, TPB, 0, stream>>>(ypc, ytc, state, hist1);
    k_scan1<<<B_IMG, 64, 0, stream>>>(state, hist1);
    k_hist2<<<NBLK, TPB, 0, stream>>>(ypc, ytc, state, hist2);
    k_scan2<<<B_IMG, 64, 0, stream>>>(state, hist2);
    k_hist3<<<NBLK, TPB, 0, stream>>>(ypc, ytc, state, hist3);
    k_scan3<<<B_IMG, 64, 0, stream>>>(state, hist3);
    k_final<<<NBLK, TPB, 0, stream>>>(ytc, ypc, tmk, state, dice_part);
    k_out<<<1, 256, 0, stream>>>(geo_part, dice_part, (float*)d_out);
}

// Round 3
// 137.167 us; speedup vs baseline: 1.1302x; 1.0534x over previous
//
#include <hip/hip_runtime.h>
#include <math.h>

#define B_IMG 16
#define HW 409600
#define HW4 102400           // HW/4 (float4 per image per stream)

// ---- k_geo geometry (LDS-staged) ----
#define GEO_PBI 100                 // blocks per image
#define GEO_NBLK (B_IMG * GEO_PBI)  // 1600
#define CHUNK 64                    // float4 per stream per wave-chunk
#define CPW 4                       // chunks per wave  (100*16 = 1600 chunks/img = HW4/64)

// ---- hist/final geometry (unchanged from r2) ----
#define P_BLK 128
#define TPB 256
#define F4_PER_BLK 800
#define NBLK2 (B_IMG * P_BLK)       // 2048

// workspace layout (bytes)
#define OFF_GEO   0                 // 1600 doubles
#define OFF_DICE  12800             // 2048*3 doubles
#define OFF_CNT   61952             // 16*2 u32
#define OFF_STATE 62080             // 16*8 u32
#define OFF_H1    62592             // 16*2048 u32
#define OFF_H2    193664            // 16*2048 u32
#define OFF_H3    324736            // 16*1024 u32
#define WS_BYTES  390272

union F4 { float4 v; float f[4]; };

__device__ __forceinline__ unsigned fkey(float x) {
    unsigned b = __float_as_uint(x);
    return b ^ ((b & 0x80000000u) ? 0xFFFFFFFFu : 0x80000000u);
}
__device__ __forceinline__ float funkey(unsigned k) {
    unsigned b = (k & 0x80000000u) ? (k ^ 0x80000000u) : ~k;
    return __uint_as_float(b);
}

__device__ __forceinline__ double wredd(double v) {
#pragma unroll
    for (int off = 32; off > 0; off >>= 1) v += __shfl_down(v, off);
    return v;
}
__device__ __forceinline__ unsigned wredu(unsigned v) {
#pragma unroll
    for (int off = 32; off > 0; off >>= 1) v += __shfl_down(v, off);
    return v;
}

// async global->LDS, 16B per lane. l must be wave-uniform; HW writes l + lane*16.
__device__ __forceinline__ void gl_lds16(const float4* g, float4* l) {
    __builtin_amdgcn_global_load_lds(
        (const __attribute__((address_space(1))) void*)g,
        (__attribute__((address_space(3))) void*)l,
        16, 0, 0);
}

// find bin b and 1-based rank r such that the n-th largest candidate falls in
// bin b with rank r among that bin's elements. blockDim.x == 64, h in LDS.
__device__ void radix_scan(const unsigned* h, int NB, unsigned n,
                           unsigned& bin_out, unsigned& r_out, bool& tgt) {
    const int lane = threadIdx.x;
    const int seg = NB >> 6;
    const int base = lane * seg;
    unsigned segsum = 0;
    for (int j = 0; j < seg; ++j) segsum += h[base + j];
    unsigned suf = segsum;
#pragma unroll
    for (int off = 1; off < 64; off <<= 1) {
        unsigned v = __shfl_down(suf, off);
        if (lane + off < 64) suf += v;
    }
    unsigned above = suf - segsum;  // counts in higher segments
    tgt = (suf >= n) && (above < n);
    bin_out = 0; r_out = 0;
    if (tgt) {
        unsigned cum = above;
        for (int j = base + seg - 1; j >= base; --j) {
            unsigned cb = cum;
            cum += h[j];
            if (cum >= n) { bin_out = (unsigned)j; r_out = n - cb; break; }
        }
    }
}

// ---------- K1: geo loss + pos/neg counts, LDS-staged 12-stream reads -------
__global__ void __launch_bounds__(256)
k_geo(const float* __restrict__ ytc, const float* __restrict__ ytg,
      const float* __restrict__ ypg, const float* __restrict__ tmk,
      unsigned* __restrict__ counts, double* __restrict__ geo_part) {
    __shared__ float4 sbuf[4][12][CHUNK];   // 48 KB, per-wave private slices
    const int tid = threadIdx.x, w = tid >> 6, lane = tid & 63;
    const int img = blockIdx.x / GEO_PBI, blkin = blockIdx.x % GEO_PBI;

    const float4* s[12];
    s[0] = (const float4*)ytc + img * HW4;
    s[1] = (const float4*)tmk + img * HW4;
#pragma unroll
    for (int c = 0; c < 5; ++c) {
        s[2 + c] = (const float4*)ytg + (img * 5 + c) * HW4;
        s[7 + c] = (const float4*)ypg + (img * 5 + c) * HW4;
    }

    float geo_f = 0.0f;
    unsigned pos = 0, neg = 0;

    for (int k = 0; k < CPW; ++k) {
        const int off = (blkin * 16 + w * CPW + k) * CHUNK + lane;
#pragma unroll
        for (int st = 0; st < 12; ++st)
            gl_lds16(s[st] + off, &sbuf[w][st][0]);
        asm volatile("s_waitcnt vmcnt(0)" ::: "memory");
        __builtin_amdgcn_sched_barrier(0);

        F4 g, m, d1g_, d2g_, d3g_, d4g_, thg_, d1p_, d2p_, d3p_, d4p_, thp_;
        g.v    = sbuf[w][0][lane];  m.v    = sbuf[w][1][lane];
        d1g_.v = sbuf[w][2][lane];  d2g_.v = sbuf[w][3][lane];
        d3g_.v = sbuf[w][4][lane];  d4g_.v = sbuf[w][5][lane];
        thg_.v = sbuf[w][6][lane];
        d1p_.v = sbuf[w][7][lane];  d2p_.v = sbuf[w][8][lane];
        d3p_.v = sbuf[w][9][lane];  d4p_.v = sbuf[w][10][lane];
        thp_.v = sbuf[w][11][lane];
#pragma unroll
        for (int j = 0; j < 4; ++j) {
            const float gv = g.f[j], mv = m.f[j];
            pos += (gv > 0.5f && mv > 0.5f) ? 1u : 0u;
            neg += (gv < 0.5f) ? 1u : 0u;
            const float ag = (d1g_.f[j] + d3g_.f[j]) * (d2g_.f[j] + d4g_.f[j]);
            const float ap = (d1p_.f[j] + d3p_.f[j]) * (d2p_.f[j] + d4p_.f[j]);
            const float wu = fminf(d2g_.f[j], d2p_.f[j]) + fminf(d4g_.f[j], d4p_.f[j]);
            const float hu = fminf(d1g_.f[j], d1p_.f[j]) + fminf(d3g_.f[j], d3p_.f[j]);
            const float ai = wu * hu;
            const float au = ag + ap - ai;
            const float la = __logf(__fdividef(au + 1.0f, ai + 1.0f));
            const float lt = 1.0f - __cosf(thp_.f[j] - thg_.f[j]);
            geo_f += (la + 20.0f * lt) * gv * mv;
        }
    }

    const double gw = wredd((double)geo_f);
    const unsigned pw = wredu(pos), nw = wredu(neg);
    __shared__ double gred[4];
    __shared__ unsigned pr[4], nr[4];
    if (lane == 0) { gred[w] = gw; pr[w] = pw; nr[w] = nw; }
    __syncthreads();
    if (tid == 0) {
        geo_part[blockIdx.x] = gred[0] + gred[1] + gred[2] + gred[3];
        atomicAdd(&counts[img * 2 + 0], pr[0] + pr[1] + pr[2] + pr[3]);
        atomicAdd(&counts[img * 2 + 1], nr[0] + nr[1] + nr[2] + nr[3]);
    }
}

// ---------- decide branch + initial n per image -----------------------------
__global__ void k_branch(const unsigned* __restrict__ counts,
                         unsigned* __restrict__ state) {
    const int img = threadIdx.x;
    if (img >= B_IMG) return;
    const unsigned pos = counts[img * 2 + 0], neg = counts[img * 2 + 1];
    unsigned branch, n = 1;
    if (pos == 0) {
        branch = 0;                      // mask1: top neg/2 of ALL scores
        n = neg / 2; if (n < 1) n = 1;
    } else {
        const unsigned n3 = min(pos * 3u, neg);
        if (n3 == 0) branch = 1;         // mask = training_mask
        else { branch = 2; n = n3; }     // mask3: top n3 of negative scores
    }
    state[img * 8 + 0] = branch;
    state[img * 8 + 2] = n;
}

// ---------- pass-1 histogram (top 11 bits), 4 lane-replicated copies --------
__global__ void __launch_bounds__(TPB)
k_hist1(const float* __restrict__ ypc, const float* __restrict__ ytc,
        const unsigned* __restrict__ state, unsigned* __restrict__ hist1) {
    const int img = blockIdx.x >> 7, blk = blockIdx.x & 127;
    const unsigned branch = state[img * 8 + 0];
    if (branch == 1) return;
    __shared__ unsigned h[4 * 2049];
    for (int j = threadIdx.x; j < 4 * 2049; j += TPB) h[j] = 0;
    __syncthreads();
    const int cbase = img * HW4 + blk * F4_PER_BLK;
    const int c = (threadIdx.x & 3) * 2049;
    const float4* sc = (const float4*)ypc;
    const float4* gt = (const float4*)ytc;
#pragma unroll
    for (int k = 0; k < 4; ++k) {
        const int t = threadIdx.x + k * TPB;
        if (t < F4_PER_BLK) {
            F4 s, g; s.v = sc[cbase + t]; g.v = gt[cbase + t];
#pragma unroll
            for (int j = 0; j < 4; ++j) {
                const bool cand = (branch == 0) || (g.f[j] < 0.5f);
                if (cand) atomicAdd(&h[c + (fkey(s.f[j]) >> 21)], 1u);
            }
        }
    }
    __syncthreads();
    for (int j = threadIdx.x; j < 2048; j += TPB) {
        const unsigned v = h[j] + h[j + 2049] + h[j + 2 * 2049] + h[j + 3 * 2049];
        if (v) atomicAdd(&hist1[img * 2048 + j], v);
    }
}

__global__ void k_scan1(unsigned* __restrict__ state, const unsigned* __restrict__ hist1) {
    const int img = blockIdx.x, lane = threadIdx.x;
    const unsigned branch = state[img * 8 + 0];
    if (branch == 1) return;
    const unsigned n = state[img * 8 + 2];
    __shared__ unsigned h[2048];
    const unsigned* g = hist1 + img * 2048;
    for (int j = lane; j < 2048; j += 64) h[j] = g[j];
    __syncthreads();
    unsigned bin, r; bool tgt;
    radix_scan(h, 2048, n, bin, r, tgt);
    if (tgt) { state[img * 8 + 1] = bin; state[img * 8 + 2] = r; }
}

// ---------- pass-2 histogram (middle 11 bits) -------------------------------
__global__ void __launch_bounds__(TPB)
k_hist2(const float* __restrict__ ypc, const float* __restrict__ ytc,
        const unsigned* __restrict__ state, unsigned* __restrict__ hist2) {
    const int img = blockIdx.x >> 7, blk = blockIdx.x & 127;
    const unsigned branch = state[img * 8 + 0];
    if (branch == 1) return;
    const unsigned pfx = state[img * 8 + 1];
    __shared__ unsigned h[2048];
    for (int j = threadIdx.x; j < 2048; j += TPB) h[j] = 0;
    __syncthreads();
    const int cbase = img * HW4 + blk * F4_PER_BLK;
    const float4* sc = (const float4*)ypc;
    const float4* gt = (const float4*)ytc;
#pragma unroll
    for (int k = 0; k < 4; ++k) {
        const int t = threadIdx.x + k * TPB;
        if (t < F4_PER_BLK) {
            F4 s, g; s.v = sc[cbase + t]; g.v = gt[cbase + t];
#pragma unroll
            for (int j = 0; j < 4; ++j) {
                const bool cand = (branch == 0) || (g.f[j] < 0.5f);
                const unsigned key = fkey(s.f[j]);
                if (cand && (key >> 21) == pfx) atomicAdd(&h[(key >> 10) & 2047u], 1u);
            }
        }
    }
    __syncthreads();
    for (int j = threadIdx.x; j < 2048; j += TPB) {
        const unsigned v = h[j]; if (v) atomicAdd(&hist2[img * 2048 + j], v);
    }
}

__global__ void k_scan2(unsigned* __restrict__ state, const unsigned* __restrict__ hist2) {
    const int img = blockIdx.x, lane = threadIdx.x;
    const unsigned branch = state[img * 8 + 0];
    if (branch == 1) return;
    const unsigned n = state[img * 8 + 2];
    __shared__ unsigned h[2048];
    const unsigned* g = hist2 + img * 2048;
    for (int j = lane; j < 2048; j += 64) h[j] = g[j];
    __syncthreads();
    unsigned bin, r; bool tgt;
    radix_scan(h, 2048, n, bin, r, tgt);
    if (tgt) {
        state[img * 8 + 1] = (state[img * 8 + 1] << 11) | bin;
        state[img * 8 + 2] = r;
    }
}

// ---------- pass-3 histogram (low 10 bits) ----------------------------------
__global__ void __launch_bounds__(TPB)
k_hist3(const float* __restrict__ ypc, const float* __restrict__ ytc,
        const unsigned* __restrict__ state, unsigned* __restrict__ hist3) {
    const int img = blockIdx.x >> 7, blk = blockIdx.x & 127;
    const unsigned branch = state[img * 8 + 0];
    if (branch == 1) return;
    const unsigned pfx = state[img * 8 + 1];  // 22-bit prefix
    __shared__ unsigned h[1024];
    for (int j = threadIdx.x; j < 1024; j += TPB) h[j] = 0;
    __syncthreads();
    const int cbase = img * HW4 + blk * F4_PER_BLK;
    const float4* sc = (const float4*)ypc;
    const float4* gt = (const float4*)ytc;
#pragma unroll
    for (int k = 0; k < 4; ++k) {
        const int t = threadIdx.x + k * TPB;
        if (t < F4_PER_BLK) {
            F4 s, g; s.v = sc[cbase + t]; g.v = gt[cbase + t];
#pragma unroll
            for (int j = 0; j < 4; ++j) {
                const bool cand = (branch == 0) || (g.f[j] < 0.5f);
                const unsigned key = fkey(s.f[j]);
                if (cand && (key >> 10) == pfx) atomicAdd(&h[key & 1023u], 1u);
            }
        }
    }
    __syncthreads();
    for (int j = threadIdx.x; j < 1024; j += TPB) {
        const unsigned v = h[j]; if (v) atomicAdd(&hist3[img * 1024 + j], v);
    }
}

__global__ void k_scan3(unsigned* __restrict__ state, const unsigned* __restrict__ hist3) {
    const int img = blockIdx.x, lane = threadIdx.x;
    const unsigned branch = state[img * 8 + 0];
    if (branch == 1) return;
    const unsigned n = state[img * 8 + 2];
    __shared__ unsigned h[1024];
    const unsigned* g = hist3 + img * 1024;
    for (int j = lane; j < 1024; j += 64) h[j] = g[j];
    __syncthreads();
    unsigned bin, r; bool tgt;
    radix_scan(h, 1024, n, bin, r, tgt);
    if (tgt) {
        const unsigned key = (state[img * 8 + 1] << 10) | bin;
        state[img * 8 + 4] = __float_as_uint(funkey(key));
    }
}

// ---------- final: OHEM mask on the fly + dice partial sums -----------------
__global__ void __launch_bounds__(TPB)
k_final(const float* __restrict__ ytc, const float* __restrict__ ypc,
        const float* __restrict__ tmk, const unsigned* __restrict__ state,
        double* __restrict__ dice_part) {
    const int img = blockIdx.x >> 7, blk = blockIdx.x & 127;
    const unsigned branch = state[img * 8 + 0];
    const float thr = __uint_as_float(state[img * 8 + 4]);
    const int cbase = img * HW4 + blk * F4_PER_BLK;
    const float4* sc = (const float4*)ypc;
    const float4* gt = (const float4*)ytc;
    const float4* tm = (const float4*)tmk;
    float di = 0.0f, dg = 0.0f, dp = 0.0f;
#pragma unroll
    for (int k = 0; k < 4; ++k) {
        const int t = threadIdx.x + k * TPB;
        if (t < F4_PER_BLK) {
            F4 s, g, m; s.v = sc[cbase + t]; g.v = gt[cbase + t]; m.v = tm[cbase + t];
#pragma unroll
            for (int j = 0; j < 4; ++j) {
                const float sv = s.f[j], gv = g.f[j], mv = m.f[j];
                float mm;
                if (branch == 0)      mm = (sv >= thr) ? 1.0f : 0.0f;
                else if (branch == 1) mm = mv;
                else                  mm = (((sv >= thr) || (gv > 0.5f)) && (mv > 0.5f)) ? 1.0f : 0.0f;
                di += gv * sv * mm;
                dg += gv * mm;
                dp += sv * mm;
            }
        }
    }
    const double a = wredd((double)di), b = wredd((double)dg), c = wredd((double)dp);
    __shared__ double r[4][3];
    const int lane = threadIdx.x & 63, wid = threadIdx.x >> 6;
    if (lane == 0) { r[wid][0] = a; r[wid][1] = b; r[wid][2] = c; }
    __syncthreads();
    if (threadIdx.x == 0) {
        dice_part[blockIdx.x * 3 + 0] = r[0][0] + r[1][0] + r[2][0] + r[3][0];
        dice_part[blockIdx.x * 3 + 1] = r[0][1] + r[1][1] + r[2][1] + r[3][1];
        dice_part[blockIdx.x * 3 + 2] = r[0][2] + r[1][2] + r[2][2] + r[3][2];
    }
}

// ---------- combine ---------------------------------------------------------
__global__ void __launch_bounds__(256)
k_out(const double* __restrict__ geo_part, const double* __restrict__ dice_part,
      float* __restrict__ out) {
    double geo = 0.0, di = 0.0, dg = 0.0, dp = 0.0;
    for (int i = threadIdx.x; i < NBLK2; i += 256) {
        if (i < GEO_NBLK) geo += geo_part[i];
        di += dice_part[i * 3 + 0];
        dg += dice_part[i * 3 + 1];
        dp += dice_part[i * 3 + 2];
    }
    geo = wredd(geo); di = wredd(di); dg = wredd(dg); dp = wredd(dp);
    __shared__ double r[4][4];
    const int lane = threadIdx.x & 63, wid = threadIdx.x >> 6;
    if (lane == 0) { r[wid][0] = geo; r[wid][1] = di; r[wid][2] = dg; r[wid][3] = dp; }
    __syncthreads();
    if (threadIdx.x == 0) {
        geo = r[0][0] + r[1][0] + r[2][0] + r[3][0];
        di  = r[0][1] + r[1][1] + r[2][1] + r[3][1];
        dg  = r[0][2] + r[1][2] + r[2][2] + r[3][2];
        dp  = r[0][3] + r[1][3] + r[2][3] + r[3][3];
        const double mean = geo / (double)((double)B_IMG * (double)HW);
        const double uni = dg + dp + 1e-05;
        const double loss = mean + 0.01 * (1.0 - 2.0 * di / uni);
        out[0] = (float)loss;
    }
}

extern "C" void kernel_launch(void* const* d_in, const int* in_sizes, int n_in,
                              void* d_out, int out_size, void* d_ws, size_t ws_size,
                              hipStream_t stream) {
    const float* ytc = (const float*)d_in[0];  // y_true_cls  (gt)
    const float* ypc = (const float*)d_in[1];  // y_pred_cls  (score)
    const float* ytg = (const float*)d_in[2];  // y_true_geo
    const float* ypg = (const float*)d_in[3];  // y_pred_geo
    const float* tmk = (const float*)d_in[4];  // training_mask

    char* ws = (char*)d_ws;
    double*   geo_part  = (double*)(ws + OFF_GEO);
    double*   dice_part = (double*)(ws + OFF_DICE);
    unsigned* counts    = (unsigned*)(ws + OFF_CNT);
    unsigned* state     = (unsigned*)(ws + OFF_STATE);
    unsigned* hist1     = (unsigned*)(ws + OFF_H1);
    unsigned* hist2     = (unsigned*)(ws + OFF_H2);
    unsigned* hist3     = (unsigned*)(ws + OFF_H3);

    hipMemsetAsync(d_ws, 0, WS_BYTES, stream);

    k_geo<<<GEO_NBLK, 256, 0, stream>>>(ytc, ytg, ypg, tmk, counts, geo_part);
    k_branch<<<1, 64, 0, stream>>>(counts, state);
    k_hist1<<<NBLK2, TPB, 0, stream>>>(ypc, ytc, state, hist1);
    k_scan1<<<B_IMG, 64, 0, stream>>>(state, hist1);
    k_hist2<<<NBLK2, TPB, 0, stream>>>(ypc, ytc, state, hist2);
    k_scan2<<<B_IMG, 64, 0, stream>>>(state, hist2);
    k_hist3<<<NBLK2, TPB, 0, stream>>>(ypc, ytc, state, hist3);
    k_scan3<<<B_IMG, 64, 0, stream>>>(state, hist3);
    k_final<<<NBLK2, TPB, 0, stream>>>(ytc, ypc, tmk, state, dice_part);
    k_out<<<1, 256, 0, stream>>>(geo_part, dice_part, (float*)d_out);
}